// Round 8
// baseline (1670.908 us; speedup 1.0000x reference)
//
#include <hip/hip_runtime.h>
#include <math.h>

#define B_ 512
#define T_ 200
#define D_ 256
#define H_ 256

typedef unsigned int   u32;
typedef unsigned short u16;
typedef _Float16 half8 __attribute__((ext_vector_type(8)));
typedef float f32x4 __attribute__((ext_vector_type(4)));
typedef u32 u32x2 __attribute__((ext_vector_type(2)));

__device__ __forceinline__ float sigmoid_f(float x) { return 1.0f / (1.0f + __expf(-x)); }
__device__ __forceinline__ float tanh_f(float x)    { return 1.0f - 2.0f / (__expf(2.0f * x) + 1.0f); }
__device__ __forceinline__ u16 f16b(float x) { union { _Float16 h; u16 u; } r; r.h = (_Float16)x; return r.u; }
__device__ __forceinline__ float f16f(u16 v) { union { u16 u; _Float16 h; } r; r.u = v; return (float)r.h; }

// Raw barrier: drain LDS ops only; global loads/stores stay in flight.
#define BARX() asm volatile("s_waitcnt lgkmcnt(0)\n\ts_barrier" ::: "memory")

// Fragment-major f16 weights: [tile][kstep][lane][8]; lane l holds
// W[k = kstep*32 + (l>>4)*8 + 0..7][col = tile*16 + (l&15)].
// g_Wt: x-part rows 0..255 (tiles 0..15 reset, 16..31 update, 32..47 cand).
// g_Wh: h-part rows 256..511 (same tiling).
__device__ __attribute__((aligned(16))) _Float16 g_Wt[48 * 8 * 64 * 8];
__device__ __attribute__((aligned(16))) _Float16 g_Wh[48 * 8 * 64 * 8];

__global__ __launch_bounds__(512) void prep_wt(
    const float* __restrict__ gk, const float* __restrict__ ck)
{
    const int  blk  = blockIdx.x;        // 0..95
    const bool isH  = blk >= 48;
    const int  ct   = isH ? blk - 48 : blk;
    const int  step = threadIdx.x >> 6;
    const int  lane = threadIdx.x & 63;
    const bool isG  = ct < 32;
    const float* W  = isG ? gk : ck;
    const int  nc   = isG ? 512 : 256;
    const int  col  = (isG ? ct : ct - 32) * 16 + (lane & 15);
    const int  k0   = step * 32 + (lane >> 4) * 8 + (isH ? 256 : 0);
    half8 v;
    #pragma unroll
    for (int j = 0; j < 8; ++j)
        v[j] = (_Float16)W[(size_t)(k0 + j) * nc + col];
    _Float16* dst = isH ? g_Wh : g_Wt;
    *(half8*)&dst[((size_t)(ct * 8 + step) * 64 + lane) * 8] = v;
}

// ============================================================================
// Projection GEMM -> packed permuted layouts (unchanged from R5-R7, verified):
//   pgI: [m][256] u32, entry e(c) = (c>>6)*64 + (c&15)*4 + ((c>>4)&3)
//        holds (reset_c | update_c<<16); pcI: [m][256] u16, same perm.
// ============================================================================
__global__ __launch_bounds__(512) __attribute__((amdgpu_waves_per_eu(2, 2)))
void proj_mfma(
    const float* __restrict__ x, const float* __restrict__ gb,
    const float* __restrict__ cb,
    u32* pgI,                     // aliases d_out: [102400][256] u32
    u16* __restrict__ pcI)        // ws: [102400][256] u16
{
    __shared__ __attribute__((aligned(16))) u32 smem[2][64][132];
    _Float16 (*xs)[264] = (_Float16(*)[264])&smem[0][0][0];

    const int tid  = threadIdx.x;
    const int m0   = blockIdx.x * 64;
    const int lane = tid & 63;
    const int w    = tid >> 6;
    const int qr4  = (lane >> 4) * 4;
    const int cl   = lane & 15;
    const int le   = (w >> 2) * 64 + cl * 4 + (w & 3);

    #pragma unroll
    for (int q = 0; q < 8; ++q) {
        int f = tid + 512 * q;
        int r = f >> 6, c = (f & 63) * 4;
        float4 v = *(const float4*)&x[(size_t)(m0 + r) * 256 + c];
        uint2 p;
        union { _Float16 h[2]; u32 u; } t0, t1;
        t0.h[0] = (_Float16)v.x; t0.h[1] = (_Float16)v.y;
        t1.h[0] = (_Float16)v.z; t1.h[1] = (_Float16)v.w;
        p.x = t0.u; p.y = t1.u;
        *(uint2*)&xs[r][c] = p;
    }
    BARX();

    half8 xf[4][8];
    #pragma unroll
    for (int jt = 0; jt < 4; ++jt)
        #pragma unroll
        for (int kc = 0; kc < 8; ++kc)
            xf[jt][kc] = *(const half8*)&xs[jt * 16 + cl][kc * 32 + (lane >> 4) * 8];
    BARX();   // xs dead; smem[0] may now be overwritten

    #pragma unroll 1
    for (int p = 0; p < 6; ++p) {
        const int it = w + 8 * p;
        const _Float16* bp = &g_Wt[(size_t)it * 4096];
        half8 bf[8];
        #pragma unroll
        for (int kc = 0; kc < 8; ++kc)
            bf[kc] = *(const half8*)&bp[(kc * 64 + lane) * 8];

        f32x4 acc[4] = {};
        #pragma unroll
        for (int kc = 0; kc < 8; ++kc)
            #pragma unroll
            for (int jt = 0; jt < 4; ++jt)
                acc[jt] = __builtin_amdgcn_mfma_f32_16x16x32_f16(
                              xf[jt][kc], bf[kc], acc[jt], 0, 0, 0);

        const int n    = it * 16 + cl;
        const float bias = (p < 4) ? gb[n] : cb[n - 512];
        const int buf  = p & 1;
        u16* s16 = (u16*)&smem[buf][0][0];

        if (p < 2) {            // reset -> low halves
            #pragma unroll
            for (int jt = 0; jt < 4; ++jt)
                #pragma unroll
                for (int r = 0; r < 4; ++r)
                    s16[(jt * 16 + qr4 + r) * 264 + le * 2] = f16b(acc[jt][r] + bias);
        } else if (p < 4) {     // update -> high halves
            #pragma unroll
            for (int jt = 0; jt < 4; ++jt)
                #pragma unroll
                for (int r = 0; r < 4; ++r)
                    s16[(jt * 16 + qr4 + r) * 264 + le * 2 + 1] = f16b(acc[jt][r] + bias);
            BARX();
            #pragma unroll
            for (int q = 0; q < 4; ++q) {
                int idx = tid + 512 * q;
                int row = idx >> 5, seg = idx & 31;
                uint4 v = *(const uint4*)&smem[buf][row][seg * 4];
                *(uint4*)&pgI[(size_t)(m0 + row) * 256 + 128 * buf + seg * 4] = v;
            }
        } else {                // cand -> u16 entries
            #pragma unroll
            for (int jt = 0; jt < 4; ++jt)
                #pragma unroll
                for (int r = 0; r < 4; ++r)
                    s16[(jt * 16 + qr4 + r) * 264 + le] = f16b(acc[jt][r] + bias);
            BARX();
            #pragma unroll
            for (int q = 0; q < 2; ++q) {
                int idx = tid + 512 * q;
                int row = idx >> 4, seg = idx & 15;
                uint4 v = *(const uint4*)((const u16*)&smem[buf][row][0] + seg * 8);
                *(uint4*)&pcI[(size_t)(m0 + row) * 256 + 128 * buf + seg * 8] = v;
            }
        }
        if (p == 2 || p == 3 || p == 4) BARX();
    }
}

// ============================================================================
// Recurrent kernel v8: PIPE-BALANCED step.
// Diagnosis R2-R7: every variant was LDS-instruction bound (256-384
// ds_read_b128/CU/step ~ 3000-4600 cy) with VMEM/MFMA idle.
// v8 splits traffic across pipes:
//  - LDS carries ONLY h/rh: merged gate pass reads ha once for all 4 MFMA
//    chains (8 ds_reads) + 8 ra reads = 128 b128/CU/step (~1550 cy).
//  - Wc streamed from L2 via VMEM each step (128 KB/CU/step ~1000 cy on the
//    parallel pipe; issued at barrier A, used after barrier B = latency-hid).
//  - Wr/Wu persistent: 128 regs = exactly the AGPR file (MFMA reads AGPR
//    directly on gfx950); arch-VGPR peak ~225 < 256.
// 32 blocks x 512 thr (8 waves), 16 rows, 2 lgkm-only barriers/step.
// ============================================================================
__global__ __launch_bounds__(512) void gru_rec8(
    const int* __restrict__ slen,
    const u32* pgI,                // aliases d_out: [m][256] u32 permuted
    const u16* __restrict__ pcI,   // ws: [m][256] u16 permuted
    float* out)                    // aliases pgI (row t stored after row t+1 read)
{
    __shared__ _Float16 h_lds[16][264];
    __shared__ _Float16 rh_lds[16][264];

    const int tid  = threadIdx.x;
    const int w    = tid >> 6;       // 0..7
    const int lane = tid & 63;
    const int qr   = lane >> 4;
    const int cl   = lane & 15;
    const int b0   = blockIdx.x * 16;

    // ---- persistent: R and U fragments, 2 tiles each = 128 regs (AGPR) ----
    half8 wR[2][8], wU[2][8];
    #pragma unroll
    for (int tt = 0; tt < 2; ++tt)
        #pragma unroll
        for (int s = 0; s < 8; ++s) {
            wR[tt][s] = *(const half8*)&g_Wh[(((size_t)(2 * w + tt) * 8 + s) * 64 + lane) * 8];
            wU[tt][s] = *(const half8*)&g_Wh[(((size_t)(16 + 2 * w + tt) * 8 + s) * 64 + lane) * 8];
        }

    for (int i = tid; i < 16 * 264; i += 512)
        ((_Float16*)h_lds)[i] = (_Float16)0.0f;
    __syncthreads();

    // seq lens packed (values <= 200 fit u8)
    u32 lenp = 0;
    #pragma unroll
    for (int r = 0; r < 4; ++r)
        lenp |= ((u32)slen[b0 + qr * 4 + r] & 255u) << (8 * r);

    const u32 eG = (u32)((w >> 1) * 64 + cl * 4 + 2 * (w & 1)); // packed entry base
    const u32 cO = (u32)(32 * w + cl);                          // out col base
    u32 rowT[4];
    #pragma unroll
    for (int r = 0; r < 4; ++r)
        rowT[r] = (u32)(b0 + qr * 4 + r) * (u32)(T_ * 256);

    // per-step streamed Wc bases (L2-resident; wave-uniform + lane*8)
    const _Float16* pC0 = &g_Wh[((size_t)(32 + 2 * w) * 4096) + lane * 8];
    const _Float16* pC1 = &g_Wh[((size_t)(33 + 2 * w) * 4096) + lane * 8];

    float hold[2][4] = {};
    float uu[2][4];

    // ---- prologue: gate proj for t=0 ----
    u32x2 cg[4];
    #pragma unroll
    for (int r = 0; r < 4; ++r)
        cg[r] = *(const u32x2*)(pgI + rowT[r] + eG);

    for (int t = 0; t < T_; ++t) {
        const u32 tb = (u32)t * 256u;
        const u32 tn = (t + 1 < T_) ? tb + 256u : tb;  // last-step re-read discarded

        BARX();                                   // A: h(t-1) visible

        // ---- issue Wc tile 0 stream NOW (used after barrier B) ----
        half8 wc0[8];
        #pragma unroll
        for (int s = 0; s < 8; ++s) wc0[s] = *(const half8*)(pC0 + s * 512);

        // ---- merged gate pass: one ha read feeds 4 MFMA chains ----
        f32x4 aR0 = {}, aR1 = {}, aU0 = {}, aU1 = {};
        #pragma unroll
        for (int s = 0; s < 8; ++s) {
            half8 ha = *(const half8*)&h_lds[cl][s * 32 + qr * 8];
            aR0 = __builtin_amdgcn_mfma_f32_16x16x32_f16(ha, wR[0][s], aR0, 0, 0, 0);
            aR1 = __builtin_amdgcn_mfma_f32_16x16x32_f16(ha, wR[1][s], aR1, 0, 0, 0);
            aU0 = __builtin_amdgcn_mfma_f32_16x16x32_f16(ha, wU[0][s], aU0, 0, 0, 0);
            aU1 = __builtin_amdgcn_mfma_f32_16x16x32_f16(ha, wU[1][s], aU1, 0, 0, 0);
        }

        // ---- issue Wc tile 1 stream ----
        half8 wc1[8];
        #pragma unroll
        for (int s = 0; s < 8; ++s) wc1[s] = *(const half8*)(pC1 + s * 512);

        // ---- finalize gates ----
        #pragma unroll
        for (int r = 0; r < 4; ++r) {
            float rv0 = sigmoid_f(aR0[r] + f16f((u16)(cg[r].x & 0xffffu)));
            float rv1 = sigmoid_f(aR1[r] + f16f((u16)(cg[r].y & 0xffffu)));
            uu[0][r]  = sigmoid_f(aU0[r] + f16f((u16)(cg[r].x >> 16)));
            uu[1][r]  = sigmoid_f(aU1[r] + f16f((u16)(cg[r].y >> 16)));
            rh_lds[qr * 4 + r][32 * w + cl]      = (_Float16)(rv0 * hold[0][r]);
            rh_lds[qr * 4 + r][32 * w + 16 + cl] = (_Float16)(rv1 * hold[1][r]);
        }

        // ---- reload gate proj t+1; load cand proj t (consumed after B) ----
        #pragma unroll
        for (int r = 0; r < 4; ++r)
            cg[r] = *(const u32x2*)(pgI + rowT[r] + tn + eG);
        u32 cc[4];
        #pragma unroll
        for (int r = 0; r < 4; ++r)
            cc[r] = *(const u32*)(pcI + rowT[r] + tb + eG);

        BARX();                                   // B: rh visible

        // ---- candidate: ra from LDS, Wc from the in-flight stream ----
        f32x4 aC0 = {}, aC1 = {};
        #pragma unroll
        for (int s = 0; s < 8; ++s) {
            half8 ra = *(const half8*)&rh_lds[cl][s * 32 + qr * 8];
            aC0 = __builtin_amdgcn_mfma_f32_16x16x32_f16(ra, wc0[s], aC0, 0, 0, 0);
            aC1 = __builtin_amdgcn_mfma_f32_16x16x32_f16(ra, wc1[s], aC1, 0, 0, 0);
        }

        // ---- finalize + stores ----
        #pragma unroll
        for (int r = 0; r < 4; ++r) {
            float cd0 = tanh_f(aC0[r] + f16f((u16)(cc[r] & 0xffffu)));
            float cd1 = tanh_f(aC1[r] + f16f((u16)(cc[r] >> 16)));
            float u0 = uu[0][r], u1 = uu[1][r];
            float hn0 = u0 * hold[0][r] + (1.0f - u0) * cd0;
            float hn1 = u1 * hold[1][r] + (1.0f - u1) * cd1;
            bool valid = t < (int)((lenp >> (8 * r)) & 255u);
            out[rowT[r] + tb + cO]      = valid ? hn0 : 0.0f;
            out[rowT[r] + tb + cO + 16] = valid ? hn1 : 0.0f;
            if (valid) {
                hold[0][r] = hn0; hold[1][r] = hn1;
                h_lds[qr * 4 + r][32 * w + cl]      = (_Float16)hn0;
                h_lds[qr * 4 + r][32 * w + 16 + cl] = (_Float16)hn1;
            }
        }
    }
}

extern "C" void kernel_launch(void* const* d_in, const int* in_sizes, int n_in,
                              void* d_out, int out_size, void* d_ws, size_t ws_size,
                              hipStream_t stream) {
    const float* x    = (const float*)d_in[0];
    const int*   slen = (const int*)  d_in[1];
    const float* gk   = (const float*)d_in[2];
    const float* gb   = (const float*)d_in[3];
    const float* ck   = (const float*)d_in[4];
    const float* cb   = (const float*)d_in[5];
    float* out = (float*)d_out;
    u32*   pgI = (u32*)d_out;   // [102400][256] u32 == 104.86 MB == out size
    u16*   pcI = (u16*)d_ws;    // [102400][256] u16 == 52.4 MB

    prep_wt<<<dim3(96), 512, 0, stream>>>(gk, ck);
    proj_mfma<<<dim3(1600), 512, 0, stream>>>(x, gb, cb, pgI, pcI);
    gru_rec8<<<dim3(32), 512, 0, stream>>>(slen, pgI, pcI, out);
}